// Round 1
// baseline (136.630 us; speedup 1.0000x reference)
//
#include <hip/hip_runtime.h>
#include <hip/hip_bf16.h>

#define B_     4
#define V_IN   12500
#define V_OUT  50000
#define C_IN   64
#define C_OUT  32
#define SPIRAL 9
#define K_NNZ  3
#define ROWS   (B_ * V_OUT)       // 200000
#define KDIM   (SPIRAL * C_IN)    // 576
#define KSTEPS (KDIM / 32)        // 18
#define WFRAG_ELEMS (KSTEPS * 2 * 64 * 8)  // 18432 bf16

typedef __attribute__((ext_vector_type(8))) short short8_t;   // 8 bf16 (4 VGPRs)
typedef __attribute__((ext_vector_type(4))) float floatx4;    // 4 fp32 acc

__device__ __forceinline__ unsigned short f32_to_bf16(float f) {
    unsigned int u = __float_as_uint(f);
    unsigned int r = u + 0x7fffu + ((u >> 16) & 1u);   // round-to-nearest-even
    return (unsigned short)(r >> 16);
}

// Kernel 1: up[b,v,c] = sum_k x[b, up_idx[v,k], c] * up_val[v,k]  -> bf16 in ws.
// blockIdx.x == ROWS/16: rearrange weight (576x32 fp32) into MFMA B-fragment
// order as bf16: w_frag[((kstep*2+ntile)*64 + lane)*8 + j] = W[kstep*32+quad*8+j][ntile*16+(lane&15)]
__global__ __launch_bounds__(256) void upsample_kernel(
    const float* __restrict__ x,
    const int* __restrict__ up_idx,
    const float* __restrict__ up_val,
    const float* __restrict__ weight,
    unsigned short* __restrict__ up_bf16,
    unsigned short* __restrict__ w_frag)
{
    int tid = threadIdx.x;
    if (blockIdx.x == ROWS / 16) {
        for (int idx = tid; idx < WFRAG_ELEMS; idx += 256) {
            int j     = idx & 7;
            int lane  = (idx >> 3) & 63;
            int ntile = (idx >> 9) & 1;
            int kstep = idx >> 10;
            int k = kstep * 32 + (lane >> 4) * 8 + j;
            int n = ntile * 16 + (lane & 15);
            w_frag[idx] = f32_to_bf16(weight[k * C_OUT + n]);
        }
        return;
    }
    int r      = blockIdx.x * 16 + (tid >> 4);   // global row in [0, 200000)
    int lane16 = tid & 15;                       // 4 channels each
    int b = r / V_OUT;
    int v = r - b * V_OUT;
    const int*   ui = up_idx + v * K_NNZ;
    const float* uv = up_val + v * K_NNZ;
    float a0 = 0.f, a1 = 0.f, a2 = 0.f, a3 = 0.f;
#pragma unroll
    for (int k = 0; k < K_NNZ; k++) {
        int u = ui[k];
        float val = uv[k];
        const float4* xp = (const float4*)(x + ((size_t)b * V_IN + u) * C_IN) + lane16;
        float4 xv = *xp;
        a0 += val * xv.x; a1 += val * xv.y; a2 += val * xv.z; a3 += val * xv.w;
    }
    ushort4 o;
    o.x = f32_to_bf16(a0); o.y = f32_to_bf16(a1);
    o.z = f32_to_bf16(a2); o.w = f32_to_bf16(a3);
    *((ushort4*)(up_bf16 + (size_t)r * C_IN) + lane16) = o;
}

// Kernel 2: y[r, n] = relu( sum_f g[r,f] * W[f,n] + bias[n] ),
// g[r, s*64+c] = up[b, spiral[v,s], c].  64 rows/block, 16 rows/wave, N=32.
__global__ __launch_bounds__(256) void gemm_kernel(
    const unsigned short* __restrict__ up_bf16,
    const int* __restrict__ spiral,
    const unsigned short* __restrict__ w_frag,
    const float* __restrict__ bias,
    float* __restrict__ out)
{
    __shared__ __align__(16) unsigned short w_lds[WFRAG_ELEMS];  // 36864 B
    int tid = threadIdx.x;
    {   // stage weight fragments to LDS, 16B per thread per iter
        const uint4* src = (const uint4*)w_frag;
        uint4* dst = (uint4*)w_lds;
        for (int i = tid; i < WFRAG_ELEMS / 8; i += 256) dst[i] = src[i];
    }
    __syncthreads();

    int wave = tid >> 6;
    int lane = tid & 63;
    int m    = lane & 15;
    int quad = lane >> 4;

    int r = blockIdx.x * 64 + wave * 16 + m;     // this lane's A-row
    int b = r / V_OUT;
    int v = r - b * V_OUT;

    const int* sp = spiral + v * SPIRAL;
    int su[SPIRAL];
#pragma unroll
    for (int s = 0; s < SPIRAL; s++) su[s] = sp[s];
    size_t base = (size_t)b * V_OUT * C_IN;      // element offset into up

    floatx4 acc0 = {0.f, 0.f, 0.f, 0.f};
    floatx4 acc1 = {0.f, 0.f, 0.f, 0.f};

#pragma unroll
    for (int kstep = 0; kstep < KSTEPS; kstep++) {
        int s   = kstep >> 1;
        int off = (kstep & 1) * 32 + quad * 8;   // within-row bf16 offset, 16B aligned
        const short8_t* ap = (const short8_t*)(up_bf16 + base + (size_t)su[s] * C_IN + off);
        short8_t afrag = *ap;
        const short8_t* bp0 = (const short8_t*)(w_lds + ((kstep * 2 + 0) * 64 + lane) * 8);
        const short8_t* bp1 = (const short8_t*)(w_lds + ((kstep * 2 + 1) * 64 + lane) * 8);
        short8_t bfrag0 = *bp0;
        short8_t bfrag1 = *bp1;
        acc0 = __builtin_amdgcn_mfma_f32_16x16x32_bf16(afrag, bfrag0, acc0, 0, 0, 0);
        acc1 = __builtin_amdgcn_mfma_f32_16x16x32_bf16(afrag, bfrag1, acc1, 0, 0, 0);
    }

    // epilogue: C/D layout col=lane&15, row=quad*4+reg
    float bias0 = bias[m];
    float bias1 = bias[16 + m];
    int row_base = blockIdx.x * 64 + wave * 16 + quad * 4;
#pragma unroll
    for (int reg = 0; reg < 4; reg++) {
        int rr = row_base + reg;
        float y0 = acc0[reg] + bias0; y0 = y0 > 0.f ? y0 : 0.f;
        float y1 = acc1[reg] + bias1; y1 = y1 > 0.f ? y1 : 0.f;
        out[(size_t)rr * C_OUT + m]      = y0;
        out[(size_t)rr * C_OUT + 16 + m] = y1;
    }
}

extern "C" void kernel_launch(void* const* d_in, const int* in_sizes, int n_in,
                              void* d_out, int out_size, void* d_ws, size_t ws_size,
                              hipStream_t stream) {
    const float* x      = (const float*)d_in[0];
    const int*   spiral = (const int*)d_in[1];
    const int*   up_idx = (const int*)d_in[2];
    const float* up_val = (const float*)d_in[3];
    const float* weight = (const float*)d_in[4];
    const float* bias   = (const float*)d_in[5];
    float* out = (float*)d_out;

    unsigned short* up_ws  = (unsigned short*)d_ws;          // 200000*64 bf16 = 25.6 MB
    unsigned short* w_frag = up_ws + (size_t)ROWS * C_IN;    // + 36864 B

    upsample_kernel<<<ROWS / 16 + 1, 256, 0, stream>>>(x, up_idx, up_val, weight, up_ws, w_frag);
    gemm_kernel<<<ROWS / 64, 256, 0, stream>>>(up_ws, spiral, w_frag, bias, out);
}